// Round 1
// baseline (3042.973 us; speedup 1.0000x reference)
//
#include <hip/hip_runtime.h>
#include <cmath>

// ---------------------------------------------------------------------------
// GCN 3-layer forward, MI355X.
// out[d] = dinv[d] * ( sum_{edges s->d} g[s] + g[d] ) + b,  g = (x@W)*dinv[row]
// deg/dinv computed once from edge_index, reused across layers.
// ---------------------------------------------------------------------------

__global__ __launch_bounds__(256) void k_fill(float* __restrict__ p, float v, int n) {
    int i = blockIdx.x * 256 + threadIdx.x;
    if (i < n) p[i] = v;
}

__global__ __launch_bounds__(256) void k_deg(const int* __restrict__ dst, int nE,
                                             float* __restrict__ deg) {
    int e = blockIdx.x * 256 + threadIdx.x;
    if (e < nE) atomicAdd(&deg[dst[e]], 1.0f);
}

__global__ __launch_bounds__(256) void k_dinv(const float* __restrict__ deg,
                                              float* __restrict__ dinv, int n) {
    int i = blockIdx.x * 256 + threadIdx.x;
    if (i < n) {
        float d = deg[i];
        dinv[i] = d > 0.f ? 1.0f / sqrtf(d) : 0.f;  // deg>=1 always (self-loop)
    }
}

// GEMM: [n x 64] @ [64 x OUT], scale rows by dinv, write g and seed acc=g
// (acc's init value IS the self-loop term).
// block = 256 threads; 16 rows per block; thread computes RPT rows of one col.
template <int OUT>
__global__ __launch_bounds__(256) void k_gemm_scale(
    const float* __restrict__ x, const float* __restrict__ W,
    const float* __restrict__ dinv, float* __restrict__ g,
    float* __restrict__ acc, int n) {
    constexpr int RPB = 16;                // rows per block
    constexpr int GRP = 256 / OUT;         // row-groups per block
    constexpr int RPT = RPB / GRP;         // rows per thread
    __shared__ float Ws[64 * OUT];
    __shared__ float xs[RPB * 64];

    const int tid = threadIdx.x;
    const int row0 = blockIdx.x * RPB;
    for (int i = tid; i < 64 * OUT; i += 256) Ws[i] = W[i];
    for (int i = tid; i < RPB * 64; i += 256) {
        int r = row0 + (i >> 6);
        xs[i] = (r < n) ? x[(size_t)r * 64 + (i & 63)] : 0.f;
    }
    __syncthreads();

    const int col = tid % OUT;
    const int rg  = tid / OUT;
    float a[RPT];
#pragma unroll
    for (int r = 0; r < RPT; ++r) a[r] = 0.f;
#pragma unroll
    for (int k = 0; k < 64; ++k) {
        float w = Ws[k * OUT + col];
#pragma unroll
        for (int r = 0; r < RPT; ++r)
            a[r] += xs[(rg * RPT + r) * 64 + k] * w;   // broadcast read per wave
    }
#pragma unroll
    for (int r = 0; r < RPT; ++r) {
        int rr = row0 + rg * RPT + r;
        if (rr < n) {
            float v = a[r] * dinv[rr];
            g[(size_t)rr * OUT + col]   = v;
            acc[(size_t)rr * OUT + col] = v;
        }
    }
}

// Edge scatter: TPE = FEAT/4 threads per edge, float4 gather + 4 f32 atomics.
template <int FEAT>
__global__ __launch_bounds__(256) void k_scatter(
    const int* __restrict__ src, const int* __restrict__ dst, int nE,
    const float* __restrict__ g, float* __restrict__ acc) {
    constexpr int TPE = FEAT / 4;
    int t = blockIdx.x * 256 + threadIdx.x;
    int e = t / TPE;
    int sub = t % TPE;
    if (e >= nE) return;
    int s = src[e];
    int d = dst[e];
    float4 v = *reinterpret_cast<const float4*>(g + (size_t)s * FEAT + sub * 4);
    float* a = acc + (size_t)d * FEAT + sub * 4;
    atomicAdd(a + 0, v.x);
    atomicAdd(a + 1, v.y);
    atomicAdd(a + 2, v.z);
    atomicAdd(a + 3, v.w);
}

// out = [elu]( dinv[row]*acc + b ), float4-vectorized.
template <int FEAT, bool ELU>
__global__ __launch_bounds__(256) void k_finalize(
    const float* __restrict__ acc, const float* __restrict__ dinv,
    const float* __restrict__ b, float* __restrict__ out, int n) {
    constexpr int C4 = FEAT / 4;
    long long i = (long long)blockIdx.x * 256 + threadIdx.x;
    long long total = (long long)n * C4;
    if (i >= total) return;
    int row = (int)(i / C4);
    int c4  = (int)(i % C4);
    float dv = dinv[row];
    float4 a  = *reinterpret_cast<const float4*>(acc + i * 4);
    float4 bb = *reinterpret_cast<const float4*>(b + c4 * 4);
    float4 o;
    o.x = dv * a.x + bb.x;
    o.y = dv * a.y + bb.y;
    o.z = dv * a.z + bb.z;
    o.w = dv * a.w + bb.w;
    if (ELU) {
        o.x = o.x > 0.f ? o.x : expm1f(o.x);
        o.y = o.y > 0.f ? o.y : expm1f(o.y);
        o.z = o.z > 0.f ? o.z : expm1f(o.z);
        o.w = o.w > 0.f ? o.w : expm1f(o.w);
    }
    *reinterpret_cast<float4*>(out + i * 4) = o;
}

extern "C" void kernel_launch(void* const* d_in, const int* in_sizes, int n_in,
                              void* d_out, int out_size, void* d_ws, size_t ws_size,
                              hipStream_t stream) {
    const float* x  = (const float*)d_in[0];
    const float* W1 = (const float*)d_in[1];
    const float* b1 = (const float*)d_in[2];
    const float* W2 = (const float*)d_in[3];
    const float* b2 = (const float*)d_in[4];
    const float* W3 = (const float*)d_in[5];
    const float* b3 = (const float*)d_in[6];
    const int*   ei = (const int*)d_in[7];     // int32 (JAX x64-disabled)

    const int N  = in_sizes[0] / 64;           // 80000
    const int E  = in_sizes[7] / 2;            // 1280000
    const int* src = ei;
    const int* dst = ei + E;

    float* ws = (float*)d_ws;
    float* dinv = ws;                          // [N]
    float* A = ws + N;                         // [N*64]
    float* B = A + (size_t)N * 64;             // [N*64]
    float* C = B + (size_t)N * 64;             // [N*64]
    float* out = (float*)d_out;                // [N*32]

    auto cdiv = [](long long a, long long b) { return (int)((a + b - 1) / b); };

    // --- degree / dinv (once; B used as scratch deg) ---
    k_fill<<<cdiv(N, 256), 256, 0, stream>>>(B, 1.0f, N);           // self-loop
    k_deg<<<cdiv(E, 256), 256, 0, stream>>>(dst, E, B);
    k_dinv<<<cdiv(N, 256), 256, 0, stream>>>(B, dinv, N);

    const int gemmBlocks = cdiv(N, 16);

    // --- layer 1: x -> C ---
    k_gemm_scale<64><<<gemmBlocks, 256, 0, stream>>>(x, W1, dinv, A, B, N);
    k_scatter<64><<<cdiv((long long)E * 16, 256), 256, 0, stream>>>(src, dst, E, A, B);
    k_finalize<64, true><<<cdiv((long long)N * 16, 256), 256, 0, stream>>>(B, dinv, b1, C, N);

    // --- layer 2: C -> A ---
    k_gemm_scale<64><<<gemmBlocks, 256, 0, stream>>>(C, W2, dinv, B, A, N);
    // note: g=B, acc=A? keep naming consistent: g goes in B? — use explicit args:
    // g=B is wrong order vs layer1; here g=B, acc handled below.
    k_scatter<64><<<cdiv((long long)E * 16, 256), 256, 0, stream>>>(src, dst, E, B, A);
    k_finalize<64, true><<<cdiv((long long)N * 16, 256), 256, 0, stream>>>(A, dinv, b2, C, N);
    // wait: layer2 input was C and we wrote C — but finalize reads A (acc) and
    // writes C only after gemm consumed C. Stream-ordered: gemm(C in) completes
    // before finalize(C out) launches its work. Safe.

    // --- layer 3: C -> d_out ---
    k_gemm_scale<32><<<gemmBlocks, 256, 0, stream>>>(C, W3, dinv, B, A, N);
    k_scatter<32><<<cdiv((long long)E * 8, 256), 256, 0, stream>>>(src, dst, E, B, A);
    k_finalize<32, false><<<cdiv((long long)N * 8, 256), 256, 0, stream>>>(A, dinv, b3, out, N);
}

// Round 2
// 670.307 us; speedup vs baseline: 4.5397x; 4.5397x over previous
//
#include <hip/hip_runtime.h>
#include <cmath>

// ---------------------------------------------------------------------------
// GCN 3-layer forward, MI355X — CSR-pull version (no f32 atomics).
//   g = (x@W) * dinv[row]
//   out[d] = elu?( dinv[d] * ( g[d] + sum_{s->d} g[s] ) + b )
// CSR (edges sorted by dst) built once per call via counting sort;
// deg/dinv derived from the same histogram (+1 self-loop).
// ---------------------------------------------------------------------------

__global__ __launch_bounds__(256) void k_zero_int(int* __restrict__ p, int n) {
    int i = blockIdx.x * 256 + threadIdx.x;
    if (i < n) p[i] = 0;
}

__global__ __launch_bounds__(256) void k_hist(const int* __restrict__ dst, int nE,
                                              int* __restrict__ cnt) {
    int e = blockIdx.x * 256 + threadIdx.x;
    if (e < nE) atomicAdd(&cnt[dst[e]], 1);
}

__global__ __launch_bounds__(256) void k_dinv(const int* __restrict__ cnt,
                                              float* __restrict__ dinv, int n) {
    int i = blockIdx.x * 256 + threadIdx.x;
    if (i < n) dinv[i] = rsqrtf((float)cnt[i] + 1.0f);  // +1 self-loop, always >0
}

// Single-block exclusive scan of cnt[0..n) -> row_start[0..n], row_start[n]=total.
__global__ __launch_bounds__(1024) void k_scan(const int* __restrict__ cnt,
                                               int* __restrict__ row_start, int n) {
    __shared__ int sums[1024];
    const int tid = threadIdx.x;
    const int chunk = (n + 1023) >> 10;
    const int lo = min(tid * chunk, n);
    const int hi = min(lo + chunk, n);
    int s = 0;
    for (int i = lo; i < hi; ++i) s += cnt[i];
    sums[tid] = s;
    __syncthreads();
    for (int off = 1; off < 1024; off <<= 1) {
        int t = (tid >= off) ? sums[tid - off] : 0;
        __syncthreads();
        sums[tid] += t;
        __syncthreads();
    }
    int run = sums[tid] - s;  // exclusive prefix of this thread's chunk
    for (int i = lo; i < hi; ++i) { row_start[i] = run; run += cnt[i]; }
    if (tid == 1023) row_start[n] = sums[1023];
}

__global__ __launch_bounds__(256) void k_fill_csr(
    const int* __restrict__ src, const int* __restrict__ dst, int nE,
    const int* __restrict__ row_start, int* __restrict__ cur, int* __restrict__ csr) {
    int e = blockIdx.x * 256 + threadIdx.x;
    if (e >= nE) return;
    int d = dst[e];
    int slot = row_start[d] + atomicAdd(&cur[d], 1);
    csr[slot] = src[e];
}

// GEMM: [n x 64] @ [64 x OUT], scale rows by dinv, write g.
// block = 256 threads; 16 rows per block.
template <int OUT>
__global__ __launch_bounds__(256) void k_gemm_scale(
    const float* __restrict__ x, const float* __restrict__ W,
    const float* __restrict__ dinv, float* __restrict__ g, int n) {
    constexpr int RPB = 16;                // rows per block
    constexpr int GRP = 256 / OUT;         // row-groups per block
    constexpr int RPT = RPB / GRP;         // rows per thread
    __shared__ float Ws[64 * OUT];
    __shared__ float xs[RPB * 64];

    const int tid = threadIdx.x;
    const int row0 = blockIdx.x * RPB;
    for (int i = tid; i < 64 * OUT; i += 256) Ws[i] = W[i];
    for (int i = tid; i < RPB * 64; i += 256) {
        int r = row0 + (i >> 6);
        xs[i] = (r < n) ? x[(size_t)r * 64 + (i & 63)] : 0.f;
    }
    __syncthreads();

    const int col = tid % OUT;
    const int rg  = tid / OUT;
    float a[RPT];
#pragma unroll
    for (int r = 0; r < RPT; ++r) a[r] = 0.f;
#pragma unroll
    for (int k = 0; k < 64; ++k) {
        float w = Ws[k * OUT + col];
#pragma unroll
        for (int r = 0; r < RPT; ++r)
            a[r] += xs[(rg * RPT + r) * 64 + k] * w;
    }
#pragma unroll
    for (int r = 0; r < RPT; ++r) {
        int rr = row0 + rg * RPT + r;
        if (rr < n) g[(size_t)rr * OUT + col] = a[r] * dinv[rr];
    }
}

// Pull-aggregate + finalize: TPN = FEAT/4 threads per node, float4 rows.
// acc = g[node] + sum_{j} g[csr[j]];  out = elu?( dinv[node]*acc + b )
template <int FEAT, bool ELU>
__global__ __launch_bounds__(256) void k_aggregate(
    const float* __restrict__ g, const int* __restrict__ row_start,
    const int* __restrict__ csr, const float* __restrict__ dinv,
    const float* __restrict__ b, float* __restrict__ out, int n) {
    constexpr int TPN = FEAT / 4;
    constexpr int NPB = 256 / TPN;
    const int tid = threadIdx.x;
    const int node = blockIdx.x * NPB + tid / TPN;
    const int sub = tid % TPN;
    if (node >= n) return;

    const int r0 = row_start[node];
    const int r1 = row_start[node + 1];
    float4 acc = *reinterpret_cast<const float4*>(g + (size_t)node * FEAT + sub * 4);
    for (int j = r0; j < r1; ++j) {
        int s = csr[j];
        float4 v = *reinterpret_cast<const float4*>(g + (size_t)s * FEAT + sub * 4);
        acc.x += v.x; acc.y += v.y; acc.z += v.z; acc.w += v.w;
    }
    const float dv = dinv[node];
    const float4 bb = *reinterpret_cast<const float4*>(b + sub * 4);
    float4 o;
    o.x = dv * acc.x + bb.x;
    o.y = dv * acc.y + bb.y;
    o.z = dv * acc.z + bb.z;
    o.w = dv * acc.w + bb.w;
    if (ELU) {
        o.x = o.x > 0.f ? o.x : expm1f(o.x);
        o.y = o.y > 0.f ? o.y : expm1f(o.y);
        o.z = o.z > 0.f ? o.z : expm1f(o.z);
        o.w = o.w > 0.f ? o.w : expm1f(o.w);
    }
    *reinterpret_cast<float4*>(out + (size_t)node * FEAT + sub * 4) = o;
}

extern "C" void kernel_launch(void* const* d_in, const int* in_sizes, int n_in,
                              void* d_out, int out_size, void* d_ws, size_t ws_size,
                              hipStream_t stream) {
    const float* x  = (const float*)d_in[0];
    const float* W1 = (const float*)d_in[1];
    const float* b1 = (const float*)d_in[2];
    const float* W2 = (const float*)d_in[3];
    const float* b2 = (const float*)d_in[4];
    const float* W3 = (const float*)d_in[5];
    const float* b3 = (const float*)d_in[6];
    const int*   ei = (const int*)d_in[7];     // int32 (JAX x64-disabled)

    const int N  = in_sizes[0] / 64;           // 80000
    const int E  = in_sizes[7] / 2;            // 1280000
    const int* src = ei;
    const int* dst = ei + E;

    // workspace layout (floats then ints; all 16B-aligned at float4 users)
    float* ws = (float*)d_ws;
    float* dinv = ws;                           // [N]
    float* A    = dinv + N;                     // [N*64]  g buffer
    float* C    = A + (size_t)N * 64;           // [N*64]  layer output
    int* cnt       = (int*)(C + (size_t)N * 64);// [N]   histogram
    int* row_start = cnt + N;                   // [N+1]
    int* cur       = row_start + N + 1;         // [N]   fill cursors
    int* csr       = cur + N;                   // [E]   src sorted by dst
    float* out = (float*)d_out;                 // [N*32]

    auto cdiv = [](long long a, long long b) { return (int)((a + b - 1) / b); };

    // --- CSR build + dinv (once per call) ---
    k_zero_int<<<cdiv(N, 256), 256, 0, stream>>>(cnt, N);
    k_hist<<<cdiv(E, 256), 256, 0, stream>>>(dst, E, cnt);
    k_dinv<<<cdiv(N, 256), 256, 0, stream>>>(cnt, dinv, N);
    k_scan<<<1, 1024, 0, stream>>>(cnt, row_start, N);
    k_zero_int<<<cdiv(N, 256), 256, 0, stream>>>(cur, N);
    k_fill_csr<<<cdiv(E, 256), 256, 0, stream>>>(src, dst, E, row_start, cur, csr);

    const int gemmBlocks = cdiv(N, 16);

    // --- layer 1: x -> C ---
    k_gemm_scale<64><<<gemmBlocks, 256, 0, stream>>>(x, W1, dinv, A, N);
    k_aggregate<64, true><<<cdiv(N, 16), 256, 0, stream>>>(A, row_start, csr, dinv, b1, C, N);

    // --- layer 2: C -> C (A as intermediate g) ---
    k_gemm_scale<64><<<gemmBlocks, 256, 0, stream>>>(C, W2, dinv, A, N);
    k_aggregate<64, true><<<cdiv(N, 16), 256, 0, stream>>>(A, row_start, csr, dinv, b2, C, N);

    // --- layer 3: C -> d_out ---
    k_gemm_scale<32><<<gemmBlocks, 256, 0, stream>>>(C, W3, dinv, A, N);
    k_aggregate<32, false><<<cdiv(N, 32), 256, 0, stream>>>(A, row_start, csr, dinv, b3, out, N);
}

// Round 3
// 572.041 us; speedup vs baseline: 5.3195x; 1.1718x over previous
//
#include <hip/hip_runtime.h>
#include <cmath>

// ---------------------------------------------------------------------------
// GCN 3-layer forward, MI355X — CSR-pull, hierarchical scan.
//   g = (x@W) * dinv[row]
//   out[d] = elu?( dinv[d] * ( g[d] + sum_{s->d} g[s] ) + b )
// ---------------------------------------------------------------------------

__global__ __launch_bounds__(256) void k_zero_int(int* __restrict__ p, int n) {
    int i = blockIdx.x * 256 + threadIdx.x;
    if (i < n) p[i] = 0;
}

__global__ __launch_bounds__(256) void k_hist(const int* __restrict__ dst, int nE,
                                              int* __restrict__ cnt) {
    int e = blockIdx.x * 256 + threadIdx.x;
    if (e < nE) atomicAdd(&cnt[dst[e]], 1);
}

// scan level 1: per-block (256-wide) sums of cnt
__global__ __launch_bounds__(256) void k_scan1(const int* __restrict__ cnt, int n,
                                               int* __restrict__ bsum) {
    __shared__ int s[256];
    int i = blockIdx.x * 256 + threadIdx.x;
    int v = (i < n) ? cnt[i] : 0;
    s[threadIdx.x] = v;
    __syncthreads();
    for (int off = 128; off > 0; off >>= 1) {
        if (threadIdx.x < off) s[threadIdx.x] += s[threadIdx.x + off];
        __syncthreads();
    }
    if (threadIdx.x == 0) bsum[blockIdx.x] = s[0];
}

// scan level 2: exclusive scan of block sums (nb <= 512), writes grand total
__global__ __launch_bounds__(512) void k_scan2(const int* __restrict__ bsum, int nb,
                                               int* __restrict__ boff,
                                               int* __restrict__ row_start, int n) {
    __shared__ int s[512];
    int v = (threadIdx.x < nb) ? bsum[threadIdx.x] : 0;
    s[threadIdx.x] = v;
    __syncthreads();
    for (int off = 1; off < 512; off <<= 1) {
        int t = (threadIdx.x >= off) ? s[threadIdx.x - off] : 0;
        __syncthreads();
        s[threadIdx.x] += t;
        __syncthreads();
    }
    if (threadIdx.x < nb) boff[threadIdx.x] = s[threadIdx.x] - v;  // exclusive
    if (threadIdx.x == nb - 1) row_start[n] = s[threadIdx.x];      // total
}

// scan level 3: per-block exclusive scan + block offset; also writes cur (=row_start)
// and dinv (from cnt, +1 self-loop).
__global__ __launch_bounds__(256) void k_scan3(const int* __restrict__ cnt, int n,
                                               const int* __restrict__ boff,
                                               int* __restrict__ row_start,
                                               int* __restrict__ cur,
                                               float* __restrict__ dinv) {
    __shared__ int s[256];
    int i = blockIdx.x * 256 + threadIdx.x;
    int v = (i < n) ? cnt[i] : 0;
    s[threadIdx.x] = v;
    __syncthreads();
    for (int off = 1; off < 256; off <<= 1) {
        int t = (threadIdx.x >= off) ? s[threadIdx.x - off] : 0;
        __syncthreads();
        s[threadIdx.x] += t;
        __syncthreads();
    }
    if (i < n) {
        int ex = boff[blockIdx.x] + s[threadIdx.x] - v;
        row_start[i] = ex;
        cur[i] = ex;
        dinv[i] = rsqrtf((float)v + 1.0f);
    }
}

__global__ __launch_bounds__(256) void k_fill_csr(
    const int* __restrict__ src, const int* __restrict__ dst, int nE,
    int* __restrict__ cur, int* __restrict__ csr) {
    int e = blockIdx.x * 256 + threadIdx.x;
    if (e >= nE) return;
    int slot = atomicAdd(&cur[dst[e]], 1);
    csr[slot] = src[e];
}

// GEMM: [n x 64] @ [64 x OUT], scale rows by dinv, write g.
template <int OUT>
__global__ __launch_bounds__(256) void k_gemm_scale(
    const float* __restrict__ x, const float* __restrict__ W,
    const float* __restrict__ dinv, float* __restrict__ g, int n) {
    constexpr int RPB = 16;                // rows per block
    constexpr int GRP = 256 / OUT;         // row-groups per block
    constexpr int RPT = RPB / GRP;         // rows per thread
    __shared__ float Ws[64 * OUT];
    __shared__ float xs[RPB * 64];

    const int tid = threadIdx.x;
    const int row0 = blockIdx.x * RPB;
    for (int i = tid; i < 64 * OUT; i += 256) Ws[i] = W[i];
    for (int i = tid; i < RPB * 64; i += 256) {
        int r = row0 + (i >> 6);
        xs[i] = (r < n) ? x[(size_t)r * 64 + (i & 63)] : 0.f;
    }
    __syncthreads();

    const int col = tid % OUT;
    const int rg  = tid / OUT;
    float a[RPT];
#pragma unroll
    for (int r = 0; r < RPT; ++r) a[r] = 0.f;
#pragma unroll
    for (int k = 0; k < 64; ++k) {
        float w = Ws[k * OUT + col];
#pragma unroll
        for (int r = 0; r < RPT; ++r)
            a[r] += xs[(rg * RPT + r) * 64 + k] * w;
    }
#pragma unroll
    for (int r = 0; r < RPT; ++r) {
        int rr = row0 + rg * RPT + r;
        if (rr < n) g[(size_t)rr * OUT + col] = a[r] * dinv[rr];
    }
}

// Pull-aggregate + finalize: TPN = FEAT/4 threads per node, float4 rows.
template <int FEAT, bool ELU>
__global__ __launch_bounds__(256) void k_aggregate(
    const float* __restrict__ g, const int* __restrict__ row_start,
    const int* __restrict__ csr, const float* __restrict__ dinv,
    const float* __restrict__ b, float* __restrict__ out, int n) {
    constexpr int TPN = FEAT / 4;
    constexpr int NPB = 256 / TPN;
    const int tid = threadIdx.x;
    const int node = blockIdx.x * NPB + tid / TPN;
    const int sub = tid % TPN;
    if (node >= n) return;

    const int r0 = row_start[node];
    const int r1 = row_start[node + 1];
    float4 acc = *reinterpret_cast<const float4*>(g + (size_t)node * FEAT + sub * 4);
    for (int j = r0; j < r1; ++j) {
        int s = csr[j];
        float4 v = *reinterpret_cast<const float4*>(g + (size_t)s * FEAT + sub * 4);
        acc.x += v.x; acc.y += v.y; acc.z += v.z; acc.w += v.w;
    }
    const float dv = dinv[node];
    const float4 bb = *reinterpret_cast<const float4*>(b + sub * 4);
    float4 o;
    o.x = dv * acc.x + bb.x;
    o.y = dv * acc.y + bb.y;
    o.z = dv * acc.z + bb.z;
    o.w = dv * acc.w + bb.w;
    if (ELU) {
        o.x = o.x > 0.f ? o.x : expm1f(o.x);
        o.y = o.y > 0.f ? o.y : expm1f(o.y);
        o.z = o.z > 0.f ? o.z : expm1f(o.z);
        o.w = o.w > 0.f ? o.w : expm1f(o.w);
    }
    *reinterpret_cast<float4*>(out + (size_t)node * FEAT + sub * 4) = o;
}

extern "C" void kernel_launch(void* const* d_in, const int* in_sizes, int n_in,
                              void* d_out, int out_size, void* d_ws, size_t ws_size,
                              hipStream_t stream) {
    const float* x  = (const float*)d_in[0];
    const float* W1 = (const float*)d_in[1];
    const float* b1 = (const float*)d_in[2];
    const float* W2 = (const float*)d_in[3];
    const float* b2 = (const float*)d_in[4];
    const float* W3 = (const float*)d_in[5];
    const float* b3 = (const float*)d_in[6];
    const int*   ei = (const int*)d_in[7];     // int32 (JAX x64-disabled)

    const int N  = in_sizes[0] / 64;           // 80000
    const int E  = in_sizes[7] / 2;            // 1280000
    const int* src = ei;
    const int* dst = ei + E;

    auto cdiv = [](long long a, long long b) { return (int)((a + b - 1) / b); };
    const int NB = cdiv(N, 256);               // scan blocks (313)

    // workspace layout
    float* ws = (float*)d_ws;
    float* dinv = ws;                           // [N]
    float* A    = dinv + N;                     // [N*64]  g buffer
    float* C    = A + (size_t)N * 64;           // [N*64]  layer output
    int* cnt       = (int*)(C + (size_t)N * 64);// [N]
    int* row_start = cnt + N;                   // [N+1]
    int* cur       = row_start + N + 1;         // [N]
    int* csr       = cur + N;                   // [E]
    int* bsum      = csr + E;                   // [NB]
    int* boff      = bsum + NB;                 // [NB]
    float* out = (float*)d_out;                 // [N*32]

    // --- CSR build + dinv (once per call) ---
    k_zero_int<<<NB, 256, 0, stream>>>(cnt, N);
    k_hist<<<cdiv(E, 256), 256, 0, stream>>>(dst, E, cnt);
    k_scan1<<<NB, 256, 0, stream>>>(cnt, N, bsum);
    k_scan2<<<1, 512, 0, stream>>>(bsum, NB, boff, row_start, N);
    k_scan3<<<NB, 256, 0, stream>>>(cnt, N, boff, row_start, cur, dinv);
    k_fill_csr<<<cdiv(E, 256), 256, 0, stream>>>(src, dst, E, cur, csr);

    const int gemmBlocks = cdiv(N, 16);

    // --- layer 1: x -> C ---
    k_gemm_scale<64><<<gemmBlocks, 256, 0, stream>>>(x, W1, dinv, A, N);
    k_aggregate<64, true><<<cdiv(N, 16), 256, 0, stream>>>(A, row_start, csr, dinv, b1, C, N);

    // --- layer 2: C -> C (A as intermediate g) ---
    k_gemm_scale<64><<<gemmBlocks, 256, 0, stream>>>(C, W2, dinv, A, N);
    k_aggregate<64, true><<<cdiv(N, 16), 256, 0, stream>>>(A, row_start, csr, dinv, b2, C, N);

    // --- layer 3: C -> d_out ---
    k_gemm_scale<32><<<gemmBlocks, 256, 0, stream>>>(C, W3, dinv, A, N);
    k_aggregate<32, false><<<cdiv(N, 32), 256, 0, stream>>>(A, row_start, csr, dinv, b3, out, N);
}

// Round 4
// 467.737 us; speedup vs baseline: 6.5057x; 1.2230x over previous
//
#include <hip/hip_runtime.h>
#include <cmath>

// ---------------------------------------------------------------------------
// GCN 3-layer forward, MI355X — CSR-pull, rank-based counting sort, MLP unroll.
//   g = (x@W) * dinv[row]
//   out[d] = elu?( dinv[d] * ( g[d] + sum_{s->d} g[s] ) + b )
// ---------------------------------------------------------------------------

__global__ __launch_bounds__(256) void k_zero_int(int* __restrict__ p, int n) {
    int i = blockIdx.x * 256 + threadIdx.x;
    if (i < n) p[i] = 0;
}

// histogram + per-edge rank within its dst row (counting-sort ticket)
__global__ __launch_bounds__(256) void k_hist(const int* __restrict__ dst, int nE,
                                              int* __restrict__ cnt,
                                              int* __restrict__ rank) {
    int e = blockIdx.x * 256 + threadIdx.x;
    if (e < nE) rank[e] = atomicAdd(&cnt[dst[e]], 1);
}

// scan level 1: per-block (256-wide) sums of cnt
__global__ __launch_bounds__(256) void k_scan1(const int* __restrict__ cnt, int n,
                                               int* __restrict__ bsum) {
    __shared__ int s[256];
    int i = blockIdx.x * 256 + threadIdx.x;
    int v = (i < n) ? cnt[i] : 0;
    s[threadIdx.x] = v;
    __syncthreads();
    for (int off = 128; off > 0; off >>= 1) {
        if (threadIdx.x < off) s[threadIdx.x] += s[threadIdx.x + off];
        __syncthreads();
    }
    if (threadIdx.x == 0) bsum[blockIdx.x] = s[0];
}

// scan level 2: exclusive scan of block sums (nb <= 512), writes grand total
__global__ __launch_bounds__(512) void k_scan2(const int* __restrict__ bsum, int nb,
                                               int* __restrict__ boff,
                                               int* __restrict__ row_start, int n) {
    __shared__ int s[512];
    int v = (threadIdx.x < nb) ? bsum[threadIdx.x] : 0;
    s[threadIdx.x] = v;
    __syncthreads();
    for (int off = 1; off < 512; off <<= 1) {
        int t = (threadIdx.x >= off) ? s[threadIdx.x - off] : 0;
        __syncthreads();
        s[threadIdx.x] += t;
        __syncthreads();
    }
    if (threadIdx.x < nb) boff[threadIdx.x] = s[threadIdx.x] - v;  // exclusive
    if (threadIdx.x == nb - 1) row_start[n] = s[threadIdx.x];      // total
}

// scan level 3: per-block exclusive scan + block offset; also writes dinv.
__global__ __launch_bounds__(256) void k_scan3(const int* __restrict__ cnt, int n,
                                               const int* __restrict__ boff,
                                               int* __restrict__ row_start,
                                               float* __restrict__ dinv) {
    __shared__ int s[256];
    int i = blockIdx.x * 256 + threadIdx.x;
    int v = (i < n) ? cnt[i] : 0;
    s[threadIdx.x] = v;
    __syncthreads();
    for (int off = 1; off < 256; off <<= 1) {
        int t = (threadIdx.x >= off) ? s[threadIdx.x - off] : 0;
        __syncthreads();
        s[threadIdx.x] += t;
        __syncthreads();
    }
    if (i < n) {
        row_start[i] = boff[blockIdx.x] + s[threadIdx.x] - v;
        dinv[i] = rsqrtf((float)v + 1.0f);  // +1 self-loop
    }
}

// atomic-free CSR fill: slot = row_start[dst] + rank
__global__ __launch_bounds__(256) void k_fill_csr(
    const int* __restrict__ src, const int* __restrict__ dst,
    const int* __restrict__ rank, const int* __restrict__ row_start,
    int nE, int* __restrict__ csr) {
    int e = blockIdx.x * 256 + threadIdx.x;
    if (e >= nE) return;
    csr[row_start[dst[e]] + rank[e]] = src[e];
}

// GEMM: [n x 64] @ [64 x OUT], scale rows by dinv, write g.
template <int OUT>
__global__ __launch_bounds__(256) void k_gemm_scale(
    const float* __restrict__ x, const float* __restrict__ W,
    const float* __restrict__ dinv, float* __restrict__ g, int n) {
    constexpr int RPB = 16;                // rows per block
    constexpr int GRP = 256 / OUT;         // row-groups per block
    constexpr int RPT = RPB / GRP;         // rows per thread
    __shared__ float Ws[64 * OUT];
    __shared__ float xs[RPB * 64];

    const int tid = threadIdx.x;
    const int row0 = blockIdx.x * RPB;
    for (int i = tid; i < 64 * OUT; i += 256) Ws[i] = W[i];
    for (int i = tid; i < RPB * 64; i += 256) {
        int r = row0 + (i >> 6);
        xs[i] = (r < n) ? x[(size_t)r * 64 + (i & 63)] : 0.f;
    }
    __syncthreads();

    const int col = tid % OUT;
    const int rg  = tid / OUT;
    float a[RPT];
#pragma unroll
    for (int r = 0; r < RPT; ++r) a[r] = 0.f;
#pragma unroll
    for (int k = 0; k < 64; ++k) {
        float w = Ws[k * OUT + col];
#pragma unroll
        for (int r = 0; r < RPT; ++r)
            a[r] += xs[(rg * RPT + r) * 64 + k] * w;
    }
#pragma unroll
    for (int r = 0; r < RPT; ++r) {
        int rr = row0 + rg * RPT + r;
        if (rr < n) g[(size_t)rr * OUT + col] = a[r] * dinv[rr];
    }
}

// Pull-aggregate + finalize: TPN = FEAT/4 threads per node, float4 rows.
// 4-way unrolled gather loop for memory-level parallelism.
template <int FEAT, bool ELU>
__global__ __launch_bounds__(256) void k_aggregate(
    const float* __restrict__ g, const int* __restrict__ row_start,
    const int* __restrict__ csr, const float* __restrict__ dinv,
    const float* __restrict__ b, float* __restrict__ out, int n) {
    constexpr int TPN = FEAT / 4;
    constexpr int NPB = 256 / TPN;
    const int tid = threadIdx.x;
    const int node = blockIdx.x * NPB + tid / TPN;
    const int sub = tid % TPN;
    if (node >= n) return;

    const int r0 = row_start[node];
    const int r1 = row_start[node + 1];
    float4 acc = *reinterpret_cast<const float4*>(g + (size_t)node * FEAT + sub * 4);

    int j = r0;
    for (; j + 4 <= r1; j += 4) {
        int s0 = csr[j], s1 = csr[j + 1], s2 = csr[j + 2], s3 = csr[j + 3];
        float4 v0 = *reinterpret_cast<const float4*>(g + (size_t)s0 * FEAT + sub * 4);
        float4 v1 = *reinterpret_cast<const float4*>(g + (size_t)s1 * FEAT + sub * 4);
        float4 v2 = *reinterpret_cast<const float4*>(g + (size_t)s2 * FEAT + sub * 4);
        float4 v3 = *reinterpret_cast<const float4*>(g + (size_t)s3 * FEAT + sub * 4);
        acc.x += v0.x + v1.x + v2.x + v3.x;
        acc.y += v0.y + v1.y + v2.y + v3.y;
        acc.z += v0.z + v1.z + v2.z + v3.z;
        acc.w += v0.w + v1.w + v2.w + v3.w;
    }
    for (; j < r1; ++j) {
        int s = csr[j];
        float4 v = *reinterpret_cast<const float4*>(g + (size_t)s * FEAT + sub * 4);
        acc.x += v.x; acc.y += v.y; acc.z += v.z; acc.w += v.w;
    }

    const float dv = dinv[node];
    const float4 bb = *reinterpret_cast<const float4*>(b + sub * 4);
    float4 o;
    o.x = dv * acc.x + bb.x;
    o.y = dv * acc.y + bb.y;
    o.z = dv * acc.z + bb.z;
    o.w = dv * acc.w + bb.w;
    if (ELU) {
        o.x = o.x > 0.f ? o.x : expm1f(o.x);
        o.y = o.y > 0.f ? o.y : expm1f(o.y);
        o.z = o.z > 0.f ? o.z : expm1f(o.z);
        o.w = o.w > 0.f ? o.w : expm1f(o.w);
    }
    *reinterpret_cast<float4*>(out + (size_t)node * FEAT + sub * 4) = o;
}

extern "C" void kernel_launch(void* const* d_in, const int* in_sizes, int n_in,
                              void* d_out, int out_size, void* d_ws, size_t ws_size,
                              hipStream_t stream) {
    const float* x  = (const float*)d_in[0];
    const float* W1 = (const float*)d_in[1];
    const float* b1 = (const float*)d_in[2];
    const float* W2 = (const float*)d_in[3];
    const float* b2 = (const float*)d_in[4];
    const float* W3 = (const float*)d_in[5];
    const float* b3 = (const float*)d_in[6];
    const int*   ei = (const int*)d_in[7];     // int32 (JAX x64-disabled)

    const int N  = in_sizes[0] / 64;           // 80000
    const int E  = in_sizes[7] / 2;            // 1280000
    const int* src = ei;
    const int* dst = ei + E;

    auto cdiv = [](long long a, long long b) { return (int)((a + b - 1) / b); };
    const int NB = cdiv(N, 256);               // scan blocks (313)

    // workspace layout
    float* ws = (float*)d_ws;
    float* dinv = ws;                           // [N]
    float* A    = dinv + N;                     // [N*64]  g buffer
    float* C    = A + (size_t)N * 64;           // [N*64]  layer output
    int* cnt       = (int*)(C + (size_t)N * 64);// [N]
    int* row_start = cnt + N;                   // [N+1]
    int* csr       = row_start + N + 1;         // [E]
    int* bsum      = csr + E;                   // [NB]
    int* boff      = bsum + NB;                 // [NB]
    int* rank      = (int*)C;                   // [E] aliases C (free until layer-1 agg)
    float* out = (float*)d_out;                 // [N*32]

    // --- CSR build + dinv (once per call) ---
    k_zero_int<<<NB, 256, 0, stream>>>(cnt, N);
    k_hist<<<cdiv(E, 256), 256, 0, stream>>>(dst, E, cnt, rank);
    k_scan1<<<NB, 256, 0, stream>>>(cnt, N, bsum);
    k_scan2<<<1, 512, 0, stream>>>(bsum, NB, boff, row_start, N);
    k_scan3<<<NB, 256, 0, stream>>>(cnt, N, boff, row_start, dinv);
    k_fill_csr<<<cdiv(E, 256), 256, 0, stream>>>(src, dst, rank, row_start, E, csr);

    const int gemmBlocks = cdiv(N, 16);

    // --- layer 1: x -> C ---
    k_gemm_scale<64><<<gemmBlocks, 256, 0, stream>>>(x, W1, dinv, A, N);
    k_aggregate<64, true><<<cdiv(N, 16), 256, 0, stream>>>(A, row_start, csr, dinv, b1, C, N);

    // --- layer 2: C -> C (A as intermediate g) ---
    k_gemm_scale<64><<<gemmBlocks, 256, 0, stream>>>(C, W2, dinv, A, N);
    k_aggregate<64, true><<<cdiv(N, 16), 256, 0, stream>>>(A, row_start, csr, dinv, b2, C, N);

    // --- layer 3: C -> d_out ---
    k_gemm_scale<32><<<gemmBlocks, 256, 0, stream>>>(C, W3, dinv, A, N);
    k_aggregate<32, false><<<cdiv(N, 32), 256, 0, stream>>>(A, row_start, csr, dinv, b3, out, N);
}

// Round 5
// 419.266 us; speedup vs baseline: 7.2578x; 1.1156x over previous
//
#include <hip/hip_runtime.h>
#include <cmath>

// ---------------------------------------------------------------------------
// GCN 3-layer forward, MI355X — CSR-pull, register-blocked GEMM.
//   g = (x@W) * dinv[row]
//   out[d] = elu?( dinv[d] * ( g[d] + sum_{s->d} g[s] ) + b )
// ---------------------------------------------------------------------------

__global__ __launch_bounds__(256) void k_zero_int(int* __restrict__ p, int n) {
    int i = blockIdx.x * 256 + threadIdx.x;
    if (i < n) p[i] = 0;
}

// histogram + per-edge rank within its dst row (counting-sort ticket)
__global__ __launch_bounds__(256) void k_hist(const int* __restrict__ dst, int nE,
                                              int* __restrict__ cnt,
                                              int* __restrict__ rank) {
    int e = blockIdx.x * 256 + threadIdx.x;
    if (e < nE) rank[e] = atomicAdd(&cnt[dst[e]], 1);
}

// scan level 1: per-block (256-wide) sums of cnt
__global__ __launch_bounds__(256) void k_scan1(const int* __restrict__ cnt, int n,
                                               int* __restrict__ bsum) {
    __shared__ int s[256];
    int i = blockIdx.x * 256 + threadIdx.x;
    int v = (i < n) ? cnt[i] : 0;
    s[threadIdx.x] = v;
    __syncthreads();
    for (int off = 128; off > 0; off >>= 1) {
        if (threadIdx.x < off) s[threadIdx.x] += s[threadIdx.x + off];
        __syncthreads();
    }
    if (threadIdx.x == 0) bsum[blockIdx.x] = s[0];
}

// scan level 2: exclusive scan of block sums (nb <= 512), writes grand total
__global__ __launch_bounds__(512) void k_scan2(const int* __restrict__ bsum, int nb,
                                               int* __restrict__ boff,
                                               int* __restrict__ row_start, int n) {
    __shared__ int s[512];
    int v = (threadIdx.x < nb) ? bsum[threadIdx.x] : 0;
    s[threadIdx.x] = v;
    __syncthreads();
    for (int off = 1; off < 512; off <<= 1) {
        int t = (threadIdx.x >= off) ? s[threadIdx.x - off] : 0;
        __syncthreads();
        s[threadIdx.x] += t;
        __syncthreads();
    }
    if (threadIdx.x < nb) boff[threadIdx.x] = s[threadIdx.x] - v;  // exclusive
    if (threadIdx.x == nb - 1) row_start[n] = s[threadIdx.x];      // total
}

// scan level 3: per-block exclusive scan + block offset; also writes dinv.
__global__ __launch_bounds__(256) void k_scan3(const int* __restrict__ cnt, int n,
                                               const int* __restrict__ boff,
                                               int* __restrict__ row_start,
                                               float* __restrict__ dinv) {
    __shared__ int s[256];
    int i = blockIdx.x * 256 + threadIdx.x;
    int v = (i < n) ? cnt[i] : 0;
    s[threadIdx.x] = v;
    __syncthreads();
    for (int off = 1; off < 256; off <<= 1) {
        int t = (threadIdx.x >= off) ? s[threadIdx.x - off] : 0;
        __syncthreads();
        s[threadIdx.x] += t;
        __syncthreads();
    }
    if (i < n) {
        row_start[i] = boff[blockIdx.x] + s[threadIdx.x] - v;
        dinv[i] = rsqrtf((float)v + 1.0f);  // +1 self-loop
    }
}

// atomic-free CSR fill: slot = row_start[dst] + rank
__global__ __launch_bounds__(256) void k_fill_csr(
    const int* __restrict__ src, const int* __restrict__ dst,
    const int* __restrict__ rank, const int* __restrict__ row_start,
    int nE, int* __restrict__ csr) {
    int e = blockIdx.x * 256 + threadIdx.x;
    if (e >= nE) return;
    csr[row_start[dst[e]] + rank[e]] = src[e];
}

// Register-blocked GEMM: [n x 64] @ [64 x OUT] -> g, rows scaled by dinv.
// Tile: ROWS x OUT, 256 threads, each thread a 4x4 accumulator.
// W staged in LDS (b128 reads, 2-way conflict = free); x streamed from
// global in K-chunks of 16 (4 rows x 16 k in registers).
template <int OUT>
__global__ __launch_bounds__(256) void k_gemm_scale(
    const float* __restrict__ x, const float* __restrict__ W,
    const float* __restrict__ dinv, float* __restrict__ g, int n) {
    constexpr int CG = OUT / 4;       // col-groups (16 or 8)
    constexpr int RG = 256 / CG;      // row-groups (16 or 32)
    constexpr int ROWS = RG * 4;      // 64 or 128
    __shared__ float Ws[64 * OUT];

    const int tid = threadIdx.x;
    // cooperative W load (contiguous float4)
    for (int i = tid * 4; i < 64 * OUT; i += 1024)
        *reinterpret_cast<float4*>(&Ws[i]) =
            *reinterpret_cast<const float4*>(&W[i]);
    __syncthreads();

    const int rg = tid / CG;          // wave-major: 16 cg lanes per rg
    const int cg = tid % CG;
    const int row0 = blockIdx.x * ROWS + rg * 4;

    float acc[4][4];
#pragma unroll
    for (int i = 0; i < 4; ++i)
#pragma unroll
        for (int j = 0; j < 4; ++j) acc[i][j] = 0.f;

#pragma unroll
    for (int kc = 0; kc < 4; ++kc) {          // K-chunks of 16
        float xr[4][16];
#pragma unroll
        for (int i = 0; i < 4; ++i) {
            const int row = row0 + i;
            if (row < n) {
                const float4* p = reinterpret_cast<const float4*>(
                    x + (size_t)row * 64 + kc * 16);
#pragma unroll
                for (int c = 0; c < 4; ++c) {
                    float4 v = p[c];
                    xr[i][c * 4 + 0] = v.x;
                    xr[i][c * 4 + 1] = v.y;
                    xr[i][c * 4 + 2] = v.z;
                    xr[i][c * 4 + 3] = v.w;
                }
            } else {
#pragma unroll
                for (int c = 0; c < 16; ++c) xr[i][c] = 0.f;
            }
        }
#pragma unroll
        for (int kk = 0; kk < 16; ++kk) {
            const int k = kc * 16 + kk;
            float4 w = *reinterpret_cast<const float4*>(&Ws[k * OUT + cg * 4]);
#pragma unroll
            for (int i = 0; i < 4; ++i) {
                acc[i][0] += xr[i][kk] * w.x;
                acc[i][1] += xr[i][kk] * w.y;
                acc[i][2] += xr[i][kk] * w.z;
                acc[i][3] += xr[i][kk] * w.w;
            }
        }
    }

#pragma unroll
    for (int i = 0; i < 4; ++i) {
        const int row = row0 + i;
        if (row < n) {
            const float dv = dinv[row];
            float4 o;
            o.x = acc[i][0] * dv;
            o.y = acc[i][1] * dv;
            o.z = acc[i][2] * dv;
            o.w = acc[i][3] * dv;
            *reinterpret_cast<float4*>(g + (size_t)row * OUT + cg * 4) = o;
        }
    }
}

// Pull-aggregate + finalize: TPN = FEAT/4 threads per node, float4 rows.
// 4-way unrolled gather loop for memory-level parallelism.
template <int FEAT, bool ELU>
__global__ __launch_bounds__(256) void k_aggregate(
    const float* __restrict__ g, const int* __restrict__ row_start,
    const int* __restrict__ csr, const float* __restrict__ dinv,
    const float* __restrict__ b, float* __restrict__ out, int n) {
    constexpr int TPN = FEAT / 4;
    constexpr int NPB = 256 / TPN;
    const int tid = threadIdx.x;
    const int node = blockIdx.x * NPB + tid / TPN;
    const int sub = tid % TPN;
    if (node >= n) return;

    const int r0 = row_start[node];
    const int r1 = row_start[node + 1];
    float4 acc = *reinterpret_cast<const float4*>(g + (size_t)node * FEAT + sub * 4);

    int j = r0;
    for (; j + 4 <= r1; j += 4) {
        int s0 = csr[j], s1 = csr[j + 1], s2 = csr[j + 2], s3 = csr[j + 3];
        float4 v0 = *reinterpret_cast<const float4*>(g + (size_t)s0 * FEAT + sub * 4);
        float4 v1 = *reinterpret_cast<const float4*>(g + (size_t)s1 * FEAT + sub * 4);
        float4 v2 = *reinterpret_cast<const float4*>(g + (size_t)s2 * FEAT + sub * 4);
        float4 v3 = *reinterpret_cast<const float4*>(g + (size_t)s3 * FEAT + sub * 4);
        acc.x += v0.x + v1.x + v2.x + v3.x;
        acc.y += v0.y + v1.y + v2.y + v3.y;
        acc.z += v0.z + v1.z + v2.z + v3.z;
        acc.w += v0.w + v1.w + v2.w + v3.w;
    }
    for (; j < r1; ++j) {
        int s = csr[j];
        float4 v = *reinterpret_cast<const float4*>(g + (size_t)s * FEAT + sub * 4);
        acc.x += v.x; acc.y += v.y; acc.z += v.z; acc.w += v.w;
    }

    const float dv = dinv[node];
    const float4 bb = *reinterpret_cast<const float4*>(b + sub * 4);
    float4 o;
    o.x = dv * acc.x + bb.x;
    o.y = dv * acc.y + bb.y;
    o.z = dv * acc.z + bb.z;
    o.w = dv * acc.w + bb.w;
    if (ELU) {
        o.x = o.x > 0.f ? o.x : expm1f(o.x);
        o.y = o.y > 0.f ? o.y : expm1f(o.y);
        o.z = o.z > 0.f ? o.z : expm1f(o.z);
        o.w = o.w > 0.f ? o.w : expm1f(o.w);
    }
    *reinterpret_cast<float4*>(out + (size_t)node * FEAT + sub * 4) = o;
}

extern "C" void kernel_launch(void* const* d_in, const int* in_sizes, int n_in,
                              void* d_out, int out_size, void* d_ws, size_t ws_size,
                              hipStream_t stream) {
    const float* x  = (const float*)d_in[0];
    const float* W1 = (const float*)d_in[1];
    const float* b1 = (const float*)d_in[2];
    const float* W2 = (const float*)d_in[3];
    const float* b2 = (const float*)d_in[4];
    const float* W3 = (const float*)d_in[5];
    const float* b3 = (const float*)d_in[6];
    const int*   ei = (const int*)d_in[7];     // int32 (JAX x64-disabled)

    const int N  = in_sizes[0] / 64;           // 80000
    const int E  = in_sizes[7] / 2;            // 1280000
    const int* src = ei;
    const int* dst = ei + E;

    auto cdiv = [](long long a, long long b) { return (int)((a + b - 1) / b); };
    const int NB = cdiv(N, 256);               // scan blocks (313)

    // workspace layout
    float* ws = (float*)d_ws;
    float* dinv = ws;                           // [N]
    float* A    = dinv + N;                     // [N*64]  g buffer
    float* C    = A + (size_t)N * 64;           // [N*64]  layer output
    int* cnt       = (int*)(C + (size_t)N * 64);// [N]
    int* row_start = cnt + N;                   // [N+1]
    int* csr       = row_start + N + 1;         // [E]
    int* bsum      = csr + E;                   // [NB]
    int* boff      = bsum + NB;                 // [NB]
    int* rank      = (int*)C;                   // [E] aliases C (free until layer-1 agg)
    float* out = (float*)d_out;                 // [N*32]

    // --- CSR build + dinv (once per call) ---
    k_zero_int<<<NB, 256, 0, stream>>>(cnt, N);
    k_hist<<<cdiv(E, 256), 256, 0, stream>>>(dst, E, cnt, rank);
    k_scan1<<<NB, 256, 0, stream>>>(cnt, N, bsum);
    k_scan2<<<1, 512, 0, stream>>>(bsum, NB, boff, row_start, N);
    k_scan3<<<NB, 256, 0, stream>>>(cnt, N, boff, row_start, dinv);
    k_fill_csr<<<cdiv(E, 256), 256, 0, stream>>>(src, dst, rank, row_start, E, csr);

    // --- layer 1: x -> C ---
    k_gemm_scale<64><<<cdiv(N, 64), 256, 0, stream>>>(x, W1, dinv, A, N);
    k_aggregate<64, true><<<cdiv(N, 16), 256, 0, stream>>>(A, row_start, csr, dinv, b1, C, N);

    // --- layer 2: C -> C (A as intermediate g) ---
    k_gemm_scale<64><<<cdiv(N, 64), 256, 0, stream>>>(C, W2, dinv, A, N);
    k_aggregate<64, true><<<cdiv(N, 16), 256, 0, stream>>>(A, row_start, csr, dinv, b2, C, N);

    // --- layer 3: C -> d_out ---
    k_gemm_scale<32><<<cdiv(N, 128), 256, 0, stream>>>(C, W3, dinv, A, N);
    k_aggregate<32, false><<<cdiv(N, 32), 256, 0, stream>>>(A, row_start, csr, dinv, b3, out, N);
}

// Round 6
// 326.591 us; speedup vs baseline: 9.3174x; 1.2838x over previous
//
#include <hip/hip_runtime.h>
#include <cmath>

// ---------------------------------------------------------------------------
// GCN 3-layer forward, MI355X — CSR-pull, LDS-staged register-blocked GEMM.
//   g = (x@W) * dinv[row]
//   out[d] = elu?( dinv[d] * ( g[d] + sum_{s->d} g[s] ) + b )
// ---------------------------------------------------------------------------

__global__ __launch_bounds__(256) void k_zero_int(int* __restrict__ p, int n) {
    int i = blockIdx.x * 256 + threadIdx.x;
    if (i < n) p[i] = 0;
}

// histogram + per-edge rank within its dst row (counting-sort ticket)
__global__ __launch_bounds__(256) void k_hist(const int* __restrict__ dst, int nE,
                                              int* __restrict__ cnt,
                                              int* __restrict__ rank) {
    int e = blockIdx.x * 256 + threadIdx.x;
    if (e < nE) rank[e] = atomicAdd(&cnt[dst[e]], 1);
}

// scan level 1: per-block (256-wide) sums of cnt
__global__ __launch_bounds__(256) void k_scan1(const int* __restrict__ cnt, int n,
                                               int* __restrict__ bsum) {
    __shared__ int s[256];
    int i = blockIdx.x * 256 + threadIdx.x;
    int v = (i < n) ? cnt[i] : 0;
    s[threadIdx.x] = v;
    __syncthreads();
    for (int off = 128; off > 0; off >>= 1) {
        if (threadIdx.x < off) s[threadIdx.x] += s[threadIdx.x + off];
        __syncthreads();
    }
    if (threadIdx.x == 0) bsum[blockIdx.x] = s[0];
}

// scan level 2: exclusive scan of block sums (nb <= 512), writes grand total
__global__ __launch_bounds__(512) void k_scan2(const int* __restrict__ bsum, int nb,
                                               int* __restrict__ boff,
                                               int* __restrict__ row_start, int n) {
    __shared__ int s[512];
    int v = (threadIdx.x < nb) ? bsum[threadIdx.x] : 0;
    s[threadIdx.x] = v;
    __syncthreads();
    for (int off = 1; off < 512; off <<= 1) {
        int t = (threadIdx.x >= off) ? s[threadIdx.x - off] : 0;
        __syncthreads();
        s[threadIdx.x] += t;
        __syncthreads();
    }
    if (threadIdx.x < nb) boff[threadIdx.x] = s[threadIdx.x] - v;  // exclusive
    if (threadIdx.x == nb - 1) row_start[n] = s[threadIdx.x];      // total
}

// scan level 3: per-block exclusive scan + block offset; also writes dinv.
__global__ __launch_bounds__(256) void k_scan3(const int* __restrict__ cnt, int n,
                                               const int* __restrict__ boff,
                                               int* __restrict__ row_start,
                                               float* __restrict__ dinv) {
    __shared__ int s[256];
    int i = blockIdx.x * 256 + threadIdx.x;
    int v = (i < n) ? cnt[i] : 0;
    s[threadIdx.x] = v;
    __syncthreads();
    for (int off = 1; off < 256; off <<= 1) {
        int t = (threadIdx.x >= off) ? s[threadIdx.x - off] : 0;
        __syncthreads();
        s[threadIdx.x] += t;
        __syncthreads();
    }
    if (i < n) {
        row_start[i] = boff[blockIdx.x] + s[threadIdx.x] - v;
        dinv[i] = rsqrtf((float)v + 1.0f);  // +1 self-loop
    }
}

// atomic-free CSR fill: slot = row_start[dst] + rank
__global__ __launch_bounds__(256) void k_fill_csr(
    const int* __restrict__ src, const int* __restrict__ dst,
    const int* __restrict__ rank, const int* __restrict__ row_start,
    int nE, int* __restrict__ csr) {
    int e = blockIdx.x * 256 + threadIdx.x;
    if (e >= nE) return;
    csr[row_start[dst[e]] + rank[e]] = src[e];
}

// LDS-staged register-blocked GEMM: [n x 64] @ [64 x OUT] -> g, rows * dinv.
// 256 threads; tile ROWS x OUT; thread = 4 rows x 4 cols accumulator.
// xs padded to 68 floats/row: rg-stride (4 rows = 1088 B) -> bank slot +16,
// so the 4 distinct xs addresses per wave fall 2-way per bank (free, m136).
template <int OUT>
__global__ __launch_bounds__(256) void k_gemm_scale(
    const float* __restrict__ x, const float* __restrict__ W,
    const float* __restrict__ dinv, float* __restrict__ g, int n) {
    constexpr int CG = OUT / 4;        // col-groups: 16 (OUT=64) / 8 (OUT=32)
    constexpr int RG = 256 / CG;       // row-groups: 16 / 32
    constexpr int ROWS = RG * 4;       // 64 / 128
    constexpr int XLD = 68;            // padded leading dim (floats), 16B-mult
    __shared__ float Ws[64 * OUT];
    __shared__ float xs[ROWS * XLD];

    const int tid = threadIdx.x;
    const int row0 = blockIdx.x * ROWS;

    // stage W (row-major [k][col]) — contiguous float4
#pragma unroll
    for (int i = tid * 4; i < 64 * OUT; i += 1024)
        *reinterpret_cast<float4*>(&Ws[i]) =
            *reinterpret_cast<const float4*>(&W[i]);

    // stage x tile into padded xs: flat float4 id covers [ROWS x 64]
#pragma unroll
    for (int it = 0; it < ROWS / 16; ++it) {
        const int flat = it * 1024 + tid * 4;   // float index in [ROWS*64]
        const int r = flat >> 6;
        const int k = flat & 63;
        float4 v;
        if (row0 + r < n)
            v = *reinterpret_cast<const float4*>(x + (size_t)(row0 + r) * 64 + k);
        else
            v = make_float4(0.f, 0.f, 0.f, 0.f);
        *reinterpret_cast<float4*>(&xs[r * XLD + k]) = v;
    }
    __syncthreads();

    const int rg = tid / CG;
    const int cg = tid % CG;
    const int r0 = rg * 4;

    float4 acc[4];
#pragma unroll
    for (int i = 0; i < 4; ++i) acc[i] = make_float4(0.f, 0.f, 0.f, 0.f);

#pragma unroll 2
    for (int kc = 0; kc < 16; ++kc) {           // K-chunks of 4
        float4 xr[4], wk[4];
#pragma unroll
        for (int i = 0; i < 4; ++i)
            xr[i] = *reinterpret_cast<const float4*>(&xs[(r0 + i) * XLD + kc * 4]);
#pragma unroll
        for (int kk = 0; kk < 4; ++kk)
            wk[kk] = *reinterpret_cast<const float4*>(&Ws[(kc * 4 + kk) * OUT + cg * 4]);
#pragma unroll
        for (int kk = 0; kk < 4; ++kk) {
            const float xv0 = (kk == 0) ? 0.f : 0.f;  // (placeholder to keep unroll simple)
#pragma unroll
            for (int i = 0; i < 4; ++i) {
                const float xv = (kk == 0) ? xr[i].x
                               : (kk == 1) ? xr[i].y
                               : (kk == 2) ? xr[i].z
                                           : xr[i].w;
                acc[i].x += xv * wk[kk].x;
                acc[i].y += xv * wk[kk].y;
                acc[i].z += xv * wk[kk].z;
                acc[i].w += xv * wk[kk].w;
            }
            (void)xv0;
        }
    }

#pragma unroll
    for (int i = 0; i < 4; ++i) {
        const int row = row0 + r0 + i;
        if (row < n) {
            const float dv = dinv[row];
            float4 o;
            o.x = acc[i].x * dv;
            o.y = acc[i].y * dv;
            o.z = acc[i].z * dv;
            o.w = acc[i].w * dv;
            *reinterpret_cast<float4*>(g + (size_t)row * OUT + cg * 4) = o;
        }
    }
}

// Pull-aggregate + finalize: TPN = FEAT/4 threads per node, float4 rows.
// 4-way unrolled gather loop for memory-level parallelism.
template <int FEAT, bool ELU>
__global__ __launch_bounds__(256) void k_aggregate(
    const float* __restrict__ g, const int* __restrict__ row_start,
    const int* __restrict__ csr, const float* __restrict__ dinv,
    const float* __restrict__ b, float* __restrict__ out, int n) {
    constexpr int TPN = FEAT / 4;
    constexpr int NPB = 256 / TPN;
    const int tid = threadIdx.x;
    const int node = blockIdx.x * NPB + tid / TPN;
    const int sub = tid % TPN;
    if (node >= n) return;

    const int r0 = row_start[node];
    const int r1 = row_start[node + 1];
    float4 acc = *reinterpret_cast<const float4*>(g + (size_t)node * FEAT + sub * 4);

    int j = r0;
    for (; j + 4 <= r1; j += 4) {
        int s0 = csr[j], s1 = csr[j + 1], s2 = csr[j + 2], s3 = csr[j + 3];
        float4 v0 = *reinterpret_cast<const float4*>(g + (size_t)s0 * FEAT + sub * 4);
        float4 v1 = *reinterpret_cast<const float4*>(g + (size_t)s1 * FEAT + sub * 4);
        float4 v2 = *reinterpret_cast<const float4*>(g + (size_t)s2 * FEAT + sub * 4);
        float4 v3 = *reinterpret_cast<const float4*>(g + (size_t)s3 * FEAT + sub * 4);
        acc.x += v0.x + v1.x + v2.x + v3.x;
        acc.y += v0.y + v1.y + v2.y + v3.y;
        acc.z += v0.z + v1.z + v2.z + v3.z;
        acc.w += v0.w + v1.w + v2.w + v3.w;
    }
    for (; j < r1; ++j) {
        int s = csr[j];
        float4 v = *reinterpret_cast<const float4*>(g + (size_t)s * FEAT + sub * 4);
        acc.x += v.x; acc.y += v.y; acc.z += v.z; acc.w += v.w;
    }

    const float dv = dinv[node];
    const float4 bb = *reinterpret_cast<const float4*>(b + sub * 4);
    float4 o;
    o.x = dv * acc.x + bb.x;
    o.y = dv * acc.y + bb.y;
    o.z = dv * acc.z + bb.z;
    o.w = dv * acc.w + bb.w;
    if (ELU) {
        o.x = o.x > 0.f ? o.x : expm1f(o.x);
        o.y = o.y > 0.f ? o.y : expm1f(o.y);
        o.z = o.z > 0.f ? o.z : expm1f(o.z);
        o.w = o.w > 0.f ? o.w : expm1f(o.w);
    }
    *reinterpret_cast<float4*>(out + (size_t)node * FEAT + sub * 4) = o;
}

extern "C" void kernel_launch(void* const* d_in, const int* in_sizes, int n_in,
                              void* d_out, int out_size, void* d_ws, size_t ws_size,
                              hipStream_t stream) {
    const float* x  = (const float*)d_in[0];
    const float* W1 = (const float*)d_in[1];
    const float* b1 = (const float*)d_in[2];
    const float* W2 = (const float*)d_in[3];
    const float* b2 = (const float*)d_in[4];
    const float* W3 = (const float*)d_in[5];
    const float* b3 = (const float*)d_in[6];
    const int*   ei = (const int*)d_in[7];     // int32 (JAX x64-disabled)

    const int N  = in_sizes[0] / 64;           // 80000
    const int E  = in_sizes[7] / 2;            // 1280000
    const int* src = ei;
    const int* dst = ei + E;

    auto cdiv = [](long long a, long long b) { return (int)((a + b - 1) / b); };
    const int NB = cdiv(N, 256);               // scan blocks (313)

    // workspace layout
    float* ws = (float*)d_ws;
    float* dinv = ws;                           // [N]
    float* A    = dinv + N;                     // [N*64]  g buffer
    float* C    = A + (size_t)N * 64;           // [N*64]  layer output
    int* cnt       = (int*)(C + (size_t)N * 64);// [N]
    int* row_start = cnt + N;                   // [N+1]
    int* csr       = row_start + N + 1;         // [E]
    int* bsum      = csr + E;                   // [NB]
    int* boff      = bsum + NB;                 // [NB]
    int* rank      = (int*)C;                   // [E] aliases C (free until layer-1 agg)
    float* out = (float*)d_out;                 // [N*32]

    // --- CSR build + dinv (once per call) ---
    k_zero_int<<<NB, 256, 0, stream>>>(cnt, N);
    k_hist<<<cdiv(E, 256), 256, 0, stream>>>(dst, E, cnt, rank);
    k_scan1<<<NB, 256, 0, stream>>>(cnt, N, bsum);
    k_scan2<<<1, 512, 0, stream>>>(bsum, NB, boff, row_start, N);
    k_scan3<<<NB, 256, 0, stream>>>(cnt, N, boff, row_start, dinv);
    k_fill_csr<<<cdiv(E, 256), 256, 0, stream>>>(src, dst, rank, row_start, E, csr);

    // --- layer 1: x -> C ---
    k_gemm_scale<64><<<cdiv(N, 64), 256, 0, stream>>>(x, W1, dinv, A, N);
    k_aggregate<64, true><<<cdiv(N, 16), 256, 0, stream>>>(A, row_start, csr, dinv, b1, C, N);

    // --- layer 2: C -> C (A as intermediate g) ---
    k_gemm_scale<64><<<cdiv(N, 64), 256, 0, stream>>>(C, W2, dinv, A, N);
    k_aggregate<64, true><<<cdiv(N, 16), 256, 0, stream>>>(A, row_start, csr, dinv, b2, C, N);

    // --- layer 3: C -> d_out ---
    k_gemm_scale<32><<<cdiv(N, 128), 256, 0, stream>>>(C, W3, dinv, A, N);
    k_aggregate<32, false><<<cdiv(N, 32), 256, 0, stream>>>(A, row_start, csr, dinv, b3, out, N);
}